// Round 2
// baseline (4326.008 us; speedup 1.0000x reference)
//
#include <hip/hip_runtime.h>
#include <math.h>

// Problem constants (fixed by the reference setup)
#define N_TOK   16384      // B*H*W = 16*32*32
#define N_E     16384
#define CDIM    256
#define LOG2E_F 1.4426950408889634f

// GEMM tiling
#define MT   64            // rows per block
#define NT   64            // codes per k-tile
#define KC   32            // C-chunk staged in LDS
#define NCH  8             // code chunks (grid.x)
#define CHSZ (N_E / NCH)   // 2048 codes per block
#define LDA  68            // padded LDS leading dim (keeps float4 alignment)

#define CAND_CAP 32768u
#define EPS_CAND 1e-4f

// ---- workspace layout (in floats) ----
#define OFF_ZFN  0u
#define OFF_EMBN 4194304u
#define OFF_EE   8388608u
#define OFF_SM   8404992u
#define OFF_SZ   8536064u
#define OFF_SE   8667136u
#define OFF_SBV  8798208u
#define OFF_SBI  8929280u
#define OFF_ML   9060352u
#define OFF_IZ   9076736u
#define OFF_IDX  9093120u
#define OFF_CS   9109504u
#define OFF_SC   9125888u
#define OFF_BT   9125904u
#define OFF_RK   9142288u   // 16384 x u64 (8-byte aligned: 9142288*4 % 8 == 0)
#define OFF_CL   9175056u   // 32768 x u32
#define OFF_CC   9207824u   // counter
// total ~9.21M floats = ~36.8 MB

__device__ __forceinline__ float blockReduceSum256(float v, float* sbuf) {
  __syncthreads();            // protect sbuf reuse across calls
  v += __shfl_down(v, 32);
  v += __shfl_down(v, 16);
  v += __shfl_down(v, 8);
  v += __shfl_down(v, 4);
  v += __shfl_down(v, 2);
  v += __shfl_down(v, 1);
  const int tid = threadIdx.x;
  if ((tid & 63) == 0) sbuf[tid >> 6] = v;
  __syncthreads();
  return sbuf[0] + sbuf[1] + sbuf[2] + sbuf[3];
}

__global__ __launch_bounds__(256) void k_zero(float* __restrict__ colsum,
                                              float* __restrict__ scalars,
                                              unsigned long long* __restrict__ rowkey,
                                              unsigned* __restrict__ candCnt) {
  const int i = blockIdx.x * 256 + threadIdx.x;
  if (i < N_E)   colsum[i] = 0.f;
  if (i < N_TOK) rowkey[i] = ~0ull;
  if (i < 8)     scalars[i] = 0.f;
  if (i == 0)    *candCnt = 0u;
}

__global__ __launch_bounds__(256) void k_norm_emb(const float* __restrict__ emb,
                                                  float* __restrict__ embn,
                                                  float* __restrict__ ee) {
  __shared__ float sbuf[4];
  const int k = blockIdx.x, c = threadIdx.x;
  const float x = emb[(size_t)k * CDIM + c];
  const float ss = blockReduceSum256(x * x, sbuf);
  const float nrm = fmaxf(sqrtf(ss), 1e-12f);
  const float y = x / nrm;
  embn[(size_t)k * CDIM + c] = y;
  const float s2 = blockReduceSum256(y * y, sbuf);   // sum(emb*emb) post-normalization, as reference
  if (c == 0) ee[k] = s2;
}

__global__ __launch_bounds__(256) void k_norm_z(const float* __restrict__ z,
                                                float* __restrict__ zfn) {
  __shared__ float sbuf[4];
  const int n = blockIdx.x, c = threadIdx.x;
  const int b = n >> 10, hw = n & 1023;
  const float x = z[((size_t)(b * CDIM + c) << 10) + hw];
  const float ss = blockReduceSum256(x * x, sbuf);
  const float nrm = fmaxf(sqrtf(ss), 1e-12f);
  zfn[(size_t)n * CDIM + c] = x / nrm;
}

// ---------- pass 1: GEMM + online softmax stats + argmax, per (chunk, row-tile) ----------
__global__ __launch_bounds__(256) void k_pass1(const float* __restrict__ zfn,
    const float* __restrict__ embn, const float* __restrict__ ee,
    float* __restrict__ sM, float* __restrict__ sZ, float* __restrict__ sE,
    float* __restrict__ sBV, int* __restrict__ sBI) {
  __shared__ float As[KC][LDA];
  __shared__ float Bs[KC][LDA];
  __shared__ float ees[NT];
  const int chunk = blockIdx.x, rt = blockIdx.y;
  const int r0 = rt * MT, k0 = chunk * CHSZ;
  const int tid = threadIdx.x, tx = tid & 15, ty = tid >> 4;
  const int c4 = tid & 7, rr = tid >> 3;

  float m[4], Zs[4], Es[4], bV[4]; int bI[4];
#pragma unroll
  for (int i = 0; i < 4; ++i) { m[i] = -1e30f; Zs[i] = 0.f; Es[i] = 0.f; bV[i] = -1e30f; bI[i] = 0x7fffffff; }

  for (int kt = 0; kt < CHSZ / NT; ++kt) {
    const int kb = k0 + kt * NT;
    float acc[4][4];
#pragma unroll
    for (int i = 0; i < 4; ++i)
#pragma unroll
      for (int j = 0; j < 4; ++j) acc[i][j] = 0.f;

    __syncthreads();                       // previous epilogue done before ees overwrite
    if (tid < NT) ees[tid] = ee[kb + tid];

    for (int s = 0; s < CDIM; s += KC) {
      __syncthreads();                     // previous stage's compute done
#pragma unroll
      for (int half = 0; half < 2; ++half) {
        const int r = rr + half * 32;
        const float4 va = *reinterpret_cast<const float4*>(&zfn[(size_t)(r0 + r) * CDIM + s + c4 * 4]);
        As[c4 * 4 + 0][r] = va.x; As[c4 * 4 + 1][r] = va.y;
        As[c4 * 4 + 2][r] = va.z; As[c4 * 4 + 3][r] = va.w;
        const float4 vb = *reinterpret_cast<const float4*>(&embn[(size_t)(kb + r) * CDIM + s + c4 * 4]);
        Bs[c4 * 4 + 0][r] = vb.x; Bs[c4 * 4 + 1][r] = vb.y;
        Bs[c4 * 4 + 2][r] = vb.z; Bs[c4 * 4 + 3][r] = vb.w;
      }
      __syncthreads();
#pragma unroll
      for (int cc = 0; cc < KC; ++cc) {
        const float4 a4 = *reinterpret_cast<const float4*>(&As[cc][ty * 4]);
        const float4 b4 = *reinterpret_cast<const float4*>(&Bs[cc][tx * 4]);
        const float av[4] = {a4.x, a4.y, a4.z, a4.w};
        const float bv[4] = {b4.x, b4.y, b4.z, b4.w};
#pragma unroll
        for (int i = 0; i < 4; ++i)
#pragma unroll
          for (int j = 0; j < 4; ++j) acc[i][j] = fmaf(av[i], bv[j], acc[i][j]);
      }
    }

    // fused epilogue: online softmax over this tile's 4x4 per thread
#pragma unroll
    for (int i = 0; i < 4; ++i) {
#pragma unroll
      for (int j = 0; j < 4; ++j) {
        const int kk = kb + tx * 4 + j;
        const float t = fmaf(2.0f, acc[i][j], -ees[tx * 4 + j]);  // = 2*dot - ||e_k||^2
        if (t > bV[i] || (t == bV[i] && kk < bI[i])) { bV[i] = t; bI[i] = kk; }
        const float l  = t * 100.0f;                               // logit (row-shift dropped)
        const float m2 = fmaxf(m[i], l);
        const float r1 = exp2f((m[i] - m2) * LOG2E_F);
        const float dl = l - m2;
        const float e  = exp2f(dl * LOG2E_F);
        Es[i] = (Es[i] - (m2 - m[i]) * Zs[i]) * r1 + dl * e;
        Zs[i] = Zs[i] * r1 + e;
        m[i]  = m2;
      }
    }
  }

  // merge the 16 tx-partials (disjoint code subsets, same rows) via shuffles
#pragma unroll
  for (int i = 0; i < 4; ++i) {
#pragma unroll
    for (int bit = 1; bit < 16; bit <<= 1) {
      const float mo  = __shfl_xor(m[i],  bit);
      const float Zo  = __shfl_xor(Zs[i], bit);
      const float Eo  = __shfl_xor(Es[i], bit);
      const float bVo = __shfl_xor(bV[i], bit);
      const int   bIo = __shfl_xor(bI[i], bit);
      const float m2 = fmaxf(m[i], mo);
      const float r1 = exp2f((m[i] - m2) * LOG2E_F);
      const float r2 = exp2f((mo  - m2) * LOG2E_F);
      Es[i] = (Es[i] - (m2 - m[i]) * Zs[i]) * r1 + (Eo - (m2 - mo) * Zo) * r2;
      Zs[i] = Zs[i] * r1 + Zo * r2;
      m[i]  = m2;
      if (bVo > bV[i] || (bVo == bV[i] && bIo < bI[i])) { bV[i] = bVo; bI[i] = bIo; }
    }
  }
  if (tx == 0) {
#pragma unroll
    for (int i = 0; i < 4; ++i) {
      const size_t o = (size_t)chunk * N_TOK + (r0 + ty * 4 + i);
      sM[o] = m[i]; sZ[o] = Zs[i]; sE[o] = Es[i]; sBV[o] = bV[i]; sBI[o] = bI[i];
    }
  }
}

// ---------- merge chunk partials -> final m, 1/Z, fp32 idx, bestT; sample entropy ----------
__global__ __launch_bounds__(256) void k_merge(const float* __restrict__ sM,
    const float* __restrict__ sZ, const float* __restrict__ sE,
    const float* __restrict__ sBV, const int* __restrict__ sBI,
    float* __restrict__ mL, float* __restrict__ invZ, int* __restrict__ idxI,
    float* __restrict__ bT, float* __restrict__ scalars) {
  __shared__ float sbuf[4];
  const int r = blockIdx.x * 256 + threadIdx.x;
  float m = -1e30f, Z = 0.f, E = 0.f, bV = -1e30f; int bI = 0x7fffffff;
  for (int c = 0; c < NCH; ++c) {
    const size_t o = (size_t)c * N_TOK + r;
    const float mc = sM[o], Zc = sZ[o], Ec = sE[o], bVc = sBV[o]; const int bIc = sBI[o];
    const float m2 = fmaxf(m, mc);
    const float r1 = exp2f((m  - m2) * LOG2E_F);
    const float r2 = exp2f((mc - m2) * LOG2E_F);
    E = (E - (m2 - m) * Z) * r1 + (Ec - (m2 - mc) * Zc) * r2;
    Z = Z * r1 + Zc * r2;
    m = m2;
    if (bVc > bV || (bVc == bV && bIc < bI)) { bV = bVc; bI = bIc; }
  }
  mL[r] = m; invZ[r] = 1.0f / Z; idxI[r] = bI; bT[r] = bV;
  const float ent = logf(Z) - E / Z;       // -sum p*logp for this row
  const float s = blockReduceSum256(ent, sbuf);
  if (threadIdx.x == 0) atomicAdd(&scalars[1], s);
}

// ---------- pass 2: recompute logits, accumulate avg_probs colsums, collect argmin candidates ----------
__global__ __launch_bounds__(256) void k_pass2(const float* __restrict__ zfn,
    const float* __restrict__ embn, const float* __restrict__ ee,
    const float* __restrict__ mL, const float* __restrict__ invZ,
    const float* __restrict__ bT, float* __restrict__ colsum,
    unsigned* __restrict__ candList, unsigned* __restrict__ candCnt) {
  __shared__ float As[KC][LDA];
  __shared__ float Bs[KC][LDA];
  __shared__ float ees[NT];
  __shared__ float csum[CHSZ];
  const int chunk = blockIdx.x, rt = blockIdx.y;
  const int r0 = rt * MT, k0 = chunk * CHSZ;
  const int tid = threadIdx.x, tx = tid & 15, ty = tid >> 4;
  const int c4 = tid & 7, rr = tid >> 3;

  for (int o = tid; o < CHSZ; o += 256) csum[o] = 0.f;
  float mr[4], izr[4], bTr[4];
#pragma unroll
  for (int i = 0; i < 4; ++i) {
    mr[i] = mL[r0 + ty * 4 + i]; izr[i] = invZ[r0 + ty * 4 + i]; bTr[i] = bT[r0 + ty * 4 + i];
  }

  for (int kt = 0; kt < CHSZ / NT; ++kt) {
    const int kb = k0 + kt * NT;
    float acc[4][4];
#pragma unroll
    for (int i = 0; i < 4; ++i)
#pragma unroll
      for (int j = 0; j < 4; ++j) acc[i][j] = 0.f;

    __syncthreads();
    if (tid < NT) ees[tid] = ee[kb + tid];

    for (int s = 0; s < CDIM; s += KC) {
      __syncthreads();
#pragma unroll
      for (int half = 0; half < 2; ++half) {
        const int r = rr + half * 32;
        const float4 va = *reinterpret_cast<const float4*>(&zfn[(size_t)(r0 + r) * CDIM + s + c4 * 4]);
        As[c4 * 4 + 0][r] = va.x; As[c4 * 4 + 1][r] = va.y;
        As[c4 * 4 + 2][r] = va.z; As[c4 * 4 + 3][r] = va.w;
        const float4 vb = *reinterpret_cast<const float4*>(&embn[(size_t)(kb + r) * CDIM + s + c4 * 4]);
        Bs[c4 * 4 + 0][r] = vb.x; Bs[c4 * 4 + 1][r] = vb.y;
        Bs[c4 * 4 + 2][r] = vb.z; Bs[c4 * 4 + 3][r] = vb.w;
      }
      __syncthreads();
#pragma unroll
      for (int cc = 0; cc < KC; ++cc) {
        const float4 a4 = *reinterpret_cast<const float4*>(&As[cc][ty * 4]);
        const float4 b4 = *reinterpret_cast<const float4*>(&Bs[cc][tx * 4]);
        const float av[4] = {a4.x, a4.y, a4.z, a4.w};
        const float bv[4] = {b4.x, b4.y, b4.z, b4.w};
#pragma unroll
        for (int i = 0; i < 4; ++i)
#pragma unroll
          for (int j = 0; j < 4; ++j) acc[i][j] = fmaf(av[i], bv[j], acc[i][j]);
      }
    }

    float cs[4] = {0.f, 0.f, 0.f, 0.f};
#pragma unroll
    for (int i = 0; i < 4; ++i)
#pragma unroll
      for (int j = 0; j < 4; ++j) {
        const float t  = fmaf(2.0f, acc[i][j], -ees[tx * 4 + j]);  // identical chain to pass1
        if (t >= bTr[i] - EPS_CAND) {                              // near-tie: fp64 re-rank later
          const unsigned slot = atomicAdd(candCnt, 1u);
          if (slot < CAND_CAP)
            candList[slot] = ((unsigned)(r0 + ty * 4 + i) << 14) | (unsigned)(kb + tx * 4 + j);
        }
        const float dl = t * 100.0f - mr[i];
        cs[j] += exp2f(dl * LOG2E_F) * izr[i];
      }
#pragma unroll
    for (int j = 0; j < 4; ++j) {
      cs[j] += __shfl_down(cs[j], 32);
      cs[j] += __shfl_down(cs[j], 16);
    }
    if ((tid & 63) < 16) {
#pragma unroll
      for (int j = 0; j < 4; ++j) atomicAdd(&csum[kt * NT + tx * 4 + j], cs[j]);
    }
  }
  __syncthreads();
  for (int o = tid; o < CHSZ; o += 256) atomicAdd(&colsum[k0 + o], csum[o]);
}

// ---------- fp64 re-rank of near-tie candidates (matches np-f64 math exactly) ----------
__global__ __launch_bounds__(64) void k_refine(const float* __restrict__ z,
    const float* __restrict__ emb, const unsigned* __restrict__ candList,
    const unsigned* __restrict__ candCnt, unsigned long long* __restrict__ rowkey) {
  const unsigned cnt = *candCnt;
  const unsigned lim = cnt < CAND_CAP ? cnt : CAND_CAP;
  const unsigned slot = blockIdx.x;
  if (slot >= lim) return;
  const unsigned pr = candList[slot];
  const int n = (int)(pr >> 14), k = (int)(pr & 0x3FFFu);
  const int b = n >> 10, hw = n & 1023;
  const int lane = threadIdx.x;
  double sz = 0.0, se = 0.0, sp = 0.0;
#pragma unroll
  for (int u = 0; u < CDIM / 64; ++u) {
    const int c = lane + u * 64;
    const double zv = (double)z[((size_t)(b * CDIM + c) << 10) + hw];
    const double ev = (double)emb[(size_t)k * CDIM + c];
    sz = fma(zv, zv, sz); se = fma(ev, ev, se); sp = fma(zv, ev, sp);
  }
  for (int off = 32; off; off >>= 1) {
    sz += __shfl_down(sz, off);
    se += __shfl_down(se, off);
    sp += __shfl_down(sp, off);
  }
  if (lane == 0) {
    const double nz = fmax(sqrt(sz), 1e-12);
    const double ne = fmax(sqrt(se), 1e-12);
    const double d = sz / (nz * nz) + se / (ne * ne) - 2.0 * sp / (nz * ne);
    // pack: 50-bit fixed-point d (resolution 2^-47 ~ 7e-15) | 14-bit idx
    const unsigned long long key =
        (((unsigned long long)(d * 140737488355328.0)) << 14) | (unsigned long long)k;
    atomicMin(&rowkey[n], key);
  }
}

__global__ __launch_bounds__(256) void k_fidx(const unsigned long long* __restrict__ rowkey,
    int* __restrict__ idxI, float* __restrict__ outIdxF) {
  const int n = blockIdx.x * 256 + threadIdx.x;
  const unsigned long long key = rowkey[n];
  int k = idxI[n];                       // fp32 fallback (unreachable in practice)
  if (key != ~0ull) k = (int)(key & 0x3FFFull);
  idxI[n] = k;
  outIdxF[n] = (float)k;
}

// ---------- z_q gather + transpose store + masked vq accumulation ----------
__global__ __launch_bounds__(256) void k_zq(const float* __restrict__ embn,
    const float* __restrict__ zfn, const int* __restrict__ idxI,
    const long long* __restrict__ qids, float* __restrict__ outZ,
    float* __restrict__ scalars) {
  __shared__ float sbuf[4];
  const int n = blockIdx.x, c = threadIdx.x;
  const int bI = idxI[n];
  const float e  = embn[(size_t)bI * CDIM + c];
  const float zf = zfn[(size_t)n * CDIM + c];
  const int b = n >> 10, hw = n & 1023;
  outZ[((size_t)(b * CDIM + c) << 10) + hw] = e;   // [B,C,H,W]
  const float d = e - zf;
  const float ss = blockReduceSum256(d * d, sbuf);
  if (c == 0) {
    const int w = n & 31;
    if ((long long)w <= qids[b]) atomicAdd(&scalars[0], ss * (1.0f / 256.0f));
  }
}

__global__ __launch_bounds__(256) void k_avgent(const float* __restrict__ colsum,
                                                float* __restrict__ scalars) {
  __shared__ float sbuf[4];
  const int i = blockIdx.x * 256 + threadIdx.x;
  const float q = colsum[i] * (1.0f / (float)N_TOK);
  const float c = q * logf(q + 1e-5f);
  const float s = blockReduceSum256(c, sbuf);
  if (threadIdx.x == 0) atomicAdd(&scalars[2], s);   // scalars[2] = -avg_entropy
}

__global__ __launch_bounds__(256) void k_final(const int* __restrict__ idxI,
    const long long* __restrict__ qids, const float* __restrict__ scalars,
    float* __restrict__ out) {
  __shared__ float sbuf[4];
  const int tid = threadIdx.x;
  int cnt = 0;
  for (int p = tid; p < 1024; p += 256) {
    const int v = idxI[p];
    bool eq = true;
    for (int b = 1; b < 16; ++b) eq = eq && (idxI[b * 1024 + p] == v);
    cnt += eq ? 1 : 0;
  }
  const float dc = blockReduceSum256((float)cnt, sbuf);
  if (tid == 0) {
    float denom = 0.f;
    for (int b = 0; b < 16; ++b) denom += (float)(qids[b] + 1ll);   // sum of un-broadcast mask
    out[4194304] = scalars[0] / denom;                               // vq_loss
    out[4194305] = 0.25f * scalars[0] / denom;                       // commit_loss
    out[4194306] = 0.1f * (scalars[1] * (1.0f / (float)N_TOK) + scalars[2]);  // entropy_loss
    out[4194307] = dc * (1.0f / 1024.0f);                            // dead_code_rate
  }
}

extern "C" void kernel_launch(void* const* d_in, const int* in_sizes, int n_in,
                              void* d_out, int out_size, void* d_ws, size_t ws_size,
                              hipStream_t stream) {
  const float*      z    = (const float*)d_in[0];
  const float*      emb  = (const float*)d_in[1];
  const long long*  qids = (const long long*)d_in[2];
  float* out = (float*)d_out;
  float* W   = (float*)d_ws;

  float* zfn    = W + OFF_ZFN;
  float* embn   = W + OFF_EMBN;
  float* ee     = W + OFF_EE;
  float* sM     = W + OFF_SM;
  float* sZ     = W + OFF_SZ;
  float* sE     = W + OFF_SE;
  float* sBV    = W + OFF_SBV;
  int*   sBI    = (int*)(W + OFF_SBI);
  float* mL     = W + OFF_ML;
  float* invZ   = W + OFF_IZ;
  int*   idxI   = (int*)(W + OFF_IDX);
  float* colsum = W + OFF_CS;
  float* scal   = W + OFF_SC;
  float* bT     = W + OFF_BT;
  unsigned long long* rowkey = (unsigned long long*)(W + OFF_RK);
  unsigned* candList = (unsigned*)(W + OFF_CL);
  unsigned* candCnt  = (unsigned*)(W + OFF_CC);

  k_zero    <<<dim3(64),              dim3(256), 0, stream>>>(colsum, scal, rowkey, candCnt);
  k_norm_emb<<<dim3(N_E),             dim3(256), 0, stream>>>(emb, embn, ee);
  k_norm_z  <<<dim3(N_TOK),           dim3(256), 0, stream>>>(z, zfn);
  k_pass1   <<<dim3(NCH, N_TOK / MT), dim3(256), 0, stream>>>(zfn, embn, ee, sM, sZ, sE, sBV, sBI);
  k_merge   <<<dim3(N_TOK / 256),     dim3(256), 0, stream>>>(sM, sZ, sE, sBV, sBI, mL, invZ, idxI,
                                                              bT, scal);
  k_pass2   <<<dim3(NCH, N_TOK / MT), dim3(256), 0, stream>>>(zfn, embn, ee, mL, invZ, bT, colsum,
                                                              candList, candCnt);
  k_refine  <<<dim3(CAND_CAP),        dim3(64),  0, stream>>>(z, emb, candList, candCnt, rowkey);
  k_fidx    <<<dim3(N_TOK / 256),     dim3(256), 0, stream>>>(rowkey, idxI, out + 4194308);
  k_zq      <<<dim3(N_TOK),           dim3(256), 0, stream>>>(embn, zfn, idxI, qids, out, scal);
  k_avgent  <<<dim3(N_E / 256),       dim3(256), 0, stream>>>(colsum, scal);
  k_final   <<<dim3(1),               dim3(256), 0, stream>>>(idxI, qids, scal, out);
}

// Round 4
// 1985.147 us; speedup vs baseline: 2.1792x; 2.1792x over previous
//
#include <hip/hip_runtime.h>
#include <math.h>

// Problem constants
#define N_TOK   16384
#define N_E     16384
#define CDIM    256
#define K3      768              // [hi|hi|lo] . [hi|lo|hi] = hi*hi + hi*lo + lo*hi
#define NCH     8
#define CHSZ    (N_E / NCH)      // 2048
#define CT_PER_BLK (CHSZ / 128)  // 16
#define L2E100  144.26950408889634f   // 100 * log2(e)
#define EPS_CAND 1e-4f
#define CAND_CAP 32768u

typedef __attribute__((ext_vector_type(8))) short short8;
typedef __attribute__((ext_vector_type(4))) float f32x4;

// ---- workspace layout (float offsets) ----
#define OFF_A3   0u          // ushort[16384*768]  = 6291456 floats
#define OFF_B3   6291456u    // ushort[16384*768]
#define OFF_EE   12582912u   // 16384
#define OFF_SM   12599296u   // 8*16384
#define OFF_SZ   12730368u
#define OFF_SE   12861440u
#define OFF_ML   12992512u   // 16384
#define OFF_IZ   13008896u
#define OFF_IDX  13025280u
#define OFF_CS   13041664u
#define OFF_SC   13058048u   // 16
#define OFF_RK   13058064u   // 16384 u64 (8B aligned)
#define OFF_CL   13090832u   // 32768 u32
#define OFF_CC   13123600u
// total ~13.12M floats = 52.5 MB

__device__ __forceinline__ unsigned short f2bf(float x) {
  unsigned u = __float_as_uint(x);
  unsigned r = (u + 0x7fffu + ((u >> 16) & 1u)) >> 16;
  return (unsigned short)r;
}
__device__ __forceinline__ float bf2f(unsigned short h) {
  return __uint_as_float(((unsigned)h) << 16);
}

__device__ __forceinline__ void async_load16(const void* g, void* l) {
  __builtin_amdgcn_global_load_lds((const __attribute__((address_space(1))) void*)g,
                                   (__attribute__((address_space(3))) void*)l, 16, 0, 0);
}

__device__ __forceinline__ float blockReduceSum256(float v, float* sbuf) {
  __syncthreads();
  v += __shfl_down(v, 32);
  v += __shfl_down(v, 16);
  v += __shfl_down(v, 8);
  v += __shfl_down(v, 4);
  v += __shfl_down(v, 2);
  v += __shfl_down(v, 1);
  const int tid = threadIdx.x;
  if ((tid & 63) == 0) sbuf[tid >> 6] = v;
  __syncthreads();
  return sbuf[0] + sbuf[1] + sbuf[2] + sbuf[3];
}

__global__ __launch_bounds__(256) void k_zero(float* __restrict__ colsum,
                                              float* __restrict__ scalars,
                                              unsigned long long* __restrict__ rowkey,
                                              unsigned* __restrict__ candCnt) {
  const int i = blockIdx.x * 256 + threadIdx.x;
  if (i < N_E)   colsum[i] = 0.f;
  if (i < N_TOK) rowkey[i] = ~0ull;
  if (i < 16)    scalars[i] = 0.f;
  if (i == 0)    *candCnt = 0u;
}

__global__ __launch_bounds__(256) void k_norm_emb(const float* __restrict__ emb,
                                                  unsigned short* __restrict__ B3,
                                                  float* __restrict__ ee) {
  __shared__ float sbuf[4];
  const int k = blockIdx.x, c = threadIdx.x;
  const float x = emb[(size_t)k * CDIM + c];
  const float ss = blockReduceSum256(x * x, sbuf);
  const float y = x / fmaxf(sqrtf(ss), 1e-12f);
  const unsigned short hi = f2bf(y);
  const unsigned short lo = f2bf(y - bf2f(hi));
  B3[(size_t)k * K3 + c]          = hi;
  B3[(size_t)k * K3 + CDIM + c]   = lo;
  B3[(size_t)k * K3 + 2*CDIM + c] = hi;
  const float s2 = blockReduceSum256(y * y, sbuf);
  if (c == 0) ee[k] = s2;
}

__global__ __launch_bounds__(256) void k_norm_z(const float* __restrict__ z,
                                                unsigned short* __restrict__ A3) {
  __shared__ float sbuf[4];
  const int n = blockIdx.x, c = threadIdx.x;
  const int b = n >> 10, hw = n & 1023;
  const float x = z[((size_t)(b * CDIM + c) << 10) + hw];
  const float ss = blockReduceSum256(x * x, sbuf);
  const float y = x / fmaxf(sqrtf(ss), 1e-12f);
  const unsigned short hi = f2bf(y);
  const unsigned short lo = f2bf(y - bf2f(hi));
  A3[(size_t)n * K3 + c]          = hi;
  A3[(size_t)n * K3 + CDIM + c]   = hi;
  A3[(size_t)n * K3 + 2*CDIM + c] = lo;
}

// ================= pass 1: MFMA GEMM + online softmax (m,Z,E in t-units) =================
// wave w owns token rows [w*32, w*32+32) x ALL 128 code cols of the tile -> per-row
// softmax state stays inside one wave (l15 shuffle-merge is complete).
__global__ __launch_bounds__(256) void k_pass1(const unsigned short* __restrict__ A3,
    const unsigned short* __restrict__ B3, const float* __restrict__ ee,
    float* __restrict__ sM, float* __restrict__ sZ, float* __restrict__ sE) {
  __shared__ alignas(16) unsigned short At[128 * 64];
  __shared__ alignas(16) unsigned short Bt[128 * 64];
  const int chunk = blockIdx.x, rt = blockIdx.y;
  const int r0 = rt * 128, k0 = chunk * CHSZ;
  const int tid = threadIdx.x, lane = tid & 63, w = tid >> 6;
  const int wr = w * 32;
  const int l15 = lane & 15, quad = lane >> 4;
  const unsigned ldsbase = (unsigned)(tid & ~63) * 16u;

  float m_[8], Z_[8], E_[8];
#pragma unroll
  for (int i = 0; i < 8; ++i) { m_[i] = -1e30f; Z_[i] = 0.f; E_[i] = 0.f; }

  for (int ct = 0; ct < CT_PER_BLK; ++ct) {
    const int kb = k0 + ct * 128;
    f32x4 acc[2][8];
#pragma unroll
    for (int ti = 0; ti < 2; ++ti)
#pragma unroll
      for (int tj = 0; tj < 8; ++tj) acc[ti][tj] = (f32x4){0.f, 0.f, 0.f, 0.f};
    float eev[8];
#pragma unroll
    for (int tj = 0; tj < 8; ++tj) eev[tj] = ee[kb + tj * 16 + l15];

    for (int s = 0; s < K3; s += 64) {
      __syncthreads();
#pragma unroll
      for (int i = 0; i < 4; ++i) {
        const int lin = i * 256 + tid, row = lin >> 3, cg = lin & 7;
        const int gcg = cg ^ (row & 7);
        async_load16((const char*)A3 + ((size_t)(r0 + row) * K3 + s + gcg * 8) * 2,
                     (char*)At + (i * 4096 + ldsbase));
        async_load16((const char*)B3 + ((size_t)(kb + row) * K3 + s + gcg * 8) * 2,
                     (char*)Bt + (i * 4096 + ldsbase));
      }
      __syncthreads();
#pragma unroll
      for (int kk = 0; kk < 2; ++kk) {
        short8 af[2], bfr[8];
#pragma unroll
        for (int ti = 0; ti < 2; ++ti)
          af[ti] = *(const short8*)&At[(wr + ti * 16 + l15) * 64 + (((kk * 4 + quad) ^ (l15 & 7)) * 8)];
#pragma unroll
        for (int tj = 0; tj < 8; ++tj)
          bfr[tj] = *(const short8*)&Bt[(tj * 16 + l15) * 64 + (((kk * 4 + quad) ^ (l15 & 7)) * 8)];
#pragma unroll
        for (int ti = 0; ti < 2; ++ti)
#pragma unroll
          for (int tj = 0; tj < 8; ++tj)
            acc[ti][tj] = __builtin_amdgcn_mfma_f32_16x16x32_bf16(af[ti], bfr[tj], acc[ti][tj], 0, 0, 0);
      }
    }

    // fused epilogue: tile max then online update (t-units; logits = 100*t)
#pragma unroll
    for (int ti = 0; ti < 2; ++ti)
#pragma unroll
      for (int r = 0; r < 4; ++r) {
        const int sI = ti * 4 + r;
        float tv[8];
#pragma unroll
        for (int tj = 0; tj < 8; ++tj) tv[tj] = fmaf(2.f, acc[ti][tj][r], -eev[tj]);
        float mt = tv[0];
#pragma unroll
        for (int tj = 1; tj < 8; ++tj) mt = fmaxf(mt, tv[tj]);
        const float mo = m_[sI];
        const float m2 = fmaxf(mo, mt);
        const float sc = exp2f((mo - m2) * L2E100);
        float Zr = Z_[sI];
        float Er = (E_[sI] - (m2 - mo) * Zr) * sc;
        Zr *= sc;
#pragma unroll
        for (int tj = 0; tj < 8; ++tj) {
          const float d = tv[tj] - m2;
          const float e = exp2f(d * L2E100);
          Zr += e;
          Er = fmaf(d, e, Er);
        }
        m_[sI] = m2; Z_[sI] = Zr; E_[sI] = Er;
      }
  }

  // merge the 16 l15-partials (disjoint code subsets, same rows)
#pragma unroll
  for (int sI = 0; sI < 8; ++sI) {
#pragma unroll
    for (int bit = 1; bit < 16; bit <<= 1) {
      const float mo = __shfl_xor(m_[sI], bit);
      const float Zo = __shfl_xor(Z_[sI], bit);
      const float Eo = __shfl_xor(E_[sI], bit);
      const float m2 = fmaxf(m_[sI], mo);
      const float s1 = exp2f((m_[sI] - m2) * L2E100);
      const float s2 = exp2f((mo - m2) * L2E100);
      E_[sI] = (E_[sI] - (m2 - m_[sI]) * Z_[sI]) * s1 + (Eo - (m2 - mo) * Zo) * s2;
      Z_[sI] = Z_[sI] * s1 + Zo * s2;
      m_[sI] = m2;
    }
  }
  if (l15 == 0) {
#pragma unroll
    for (int ti = 0; ti < 2; ++ti)
#pragma unroll
      for (int r = 0; r < 4; ++r) {
        const int gr = r0 + wr + ti * 16 + quad * 4 + r;
        const size_t o = (size_t)chunk * N_TOK + gr;
        sM[o] = m_[ti * 4 + r]; sZ[o] = Z_[ti * 4 + r]; sE[o] = E_[ti * 4 + r];
      }
  }
}

// ---------- merge chunk partials -> final m (t-units), 1/Z; sample entropy ----------
__global__ __launch_bounds__(256) void k_merge(const float* __restrict__ sM,
    const float* __restrict__ sZ, const float* __restrict__ sE,
    float* __restrict__ mL, float* __restrict__ invZ, float* __restrict__ scalars) {
  __shared__ float sbuf[4];
  const int r = blockIdx.x * 256 + threadIdx.x;
  float m = -1e30f, Z = 0.f, E = 0.f;
  for (int c = 0; c < NCH; ++c) {
    const size_t o = (size_t)c * N_TOK + r;
    const float mc = sM[o], Zc = sZ[o], Ec = sE[o];
    const float m2 = fmaxf(m, mc);
    const float s1 = exp2f((m - m2) * L2E100);
    const float s2 = exp2f((mc - m2) * L2E100);
    E = (E - (m2 - m) * Z) * s1 + (Ec - (m2 - mc) * Zc) * s2;
    Z = Z * s1 + Zc * s2;
    m = m2;
  }
  mL[r] = m; invZ[r] = 1.0f / Z;
  const float ent = logf(Z) - 100.f * E / Z;   // -sum p*logp (logits = 100*t)
  const float s = blockReduceSum256(ent, sbuf);
  if (threadIdx.x == 0) atomicAdd(&scalars[1], s);
}

// ================= pass 2: MFMA GEMM + colsum + argmin candidates =================
__global__ __launch_bounds__(256) void k_pass2(const unsigned short* __restrict__ A3,
    const unsigned short* __restrict__ B3, const float* __restrict__ ee,
    const float* __restrict__ mL, const float* __restrict__ invZ,
    float* __restrict__ colsum, unsigned* __restrict__ candList,
    unsigned* __restrict__ candCnt) {
  __shared__ alignas(16) unsigned short At[128 * 64];
  __shared__ alignas(16) unsigned short Bt[128 * 64];
  const int chunk = blockIdx.x, rt = blockIdx.y;
  const int r0 = rt * 128, k0 = chunk * CHSZ;
  const int tid = threadIdx.x, lane = tid & 63, w = tid >> 6;
  const int wr = w * 32;
  const int l15 = lane & 15, quad = lane >> 4;
  const unsigned ldsbase = (unsigned)(tid & ~63) * 16u;

  float mr[8], izr[8], cr[8];
#pragma unroll
  for (int ti = 0; ti < 2; ++ti)
#pragma unroll
    for (int r = 0; r < 4; ++r) {
      const int gr = r0 + wr + ti * 16 + quad * 4 + r;
      mr[ti * 4 + r]  = mL[gr];
      izr[ti * 4 + r] = invZ[gr];
      cr[ti * 4 + r]  = -mL[gr] * L2E100;
    }

  for (int ct = 0; ct < CT_PER_BLK; ++ct) {
    const int kb = k0 + ct * 128;
    f32x4 acc[2][8];
#pragma unroll
    for (int ti = 0; ti < 2; ++ti)
#pragma unroll
      for (int tj = 0; tj < 8; ++tj) acc[ti][tj] = (f32x4){0.f, 0.f, 0.f, 0.f};
    float eev[8];
#pragma unroll
    for (int tj = 0; tj < 8; ++tj) eev[tj] = ee[kb + tj * 16 + l15];

    for (int s = 0; s < K3; s += 64) {
      __syncthreads();
#pragma unroll
      for (int i = 0; i < 4; ++i) {
        const int lin = i * 256 + tid, row = lin >> 3, cg = lin & 7;
        const int gcg = cg ^ (row & 7);
        async_load16((const char*)A3 + ((size_t)(r0 + row) * K3 + s + gcg * 8) * 2,
                     (char*)At + (i * 4096 + ldsbase));
        async_load16((const char*)B3 + ((size_t)(kb + row) * K3 + s + gcg * 8) * 2,
                     (char*)Bt + (i * 4096 + ldsbase));
      }
      __syncthreads();
#pragma unroll
      for (int kk = 0; kk < 2; ++kk) {
        short8 af[2], bfr[8];
#pragma unroll
        for (int ti = 0; ti < 2; ++ti)
          af[ti] = *(const short8*)&At[(wr + ti * 16 + l15) * 64 + (((kk * 4 + quad) ^ (l15 & 7)) * 8)];
#pragma unroll
        for (int tj = 0; tj < 8; ++tj)
          bfr[tj] = *(const short8*)&Bt[(tj * 16 + l15) * 64 + (((kk * 4 + quad) ^ (l15 & 7)) * 8)];
#pragma unroll
        for (int ti = 0; ti < 2; ++ti)
#pragma unroll
          for (int tj = 0; tj < 8; ++tj)
            acc[ti][tj] = __builtin_amdgcn_mfma_f32_16x16x32_bf16(af[ti], bfr[tj], acc[ti][tj], 0, 0, 0);
      }
    }

    float cs[8];
#pragma unroll
    for (int tj = 0; tj < 8; ++tj) cs[tj] = 0.f;
#pragma unroll
    for (int ti = 0; ti < 2; ++ti)
#pragma unroll
      for (int r = 0; r < 4; ++r) {
        const int sI = ti * 4 + r;
#pragma unroll
        for (int tj = 0; tj < 8; ++tj) {
          const float t = fmaf(2.f, acc[ti][tj][r], -eev[tj]);   // identical chain to pass1
          if (t >= mr[sI] - EPS_CAND) {
            const unsigned slot = atomicAdd(candCnt, 1u);
            if (slot < CAND_CAP) {
              const unsigned row = (unsigned)(r0 + wr + ti * 16 + quad * 4 + r);
              const unsigned col = (unsigned)(kb + tj * 16 + l15);
              candList[slot] = (row << 14) | col;
            }
          }
          const float e = exp2f(fmaf(t, L2E100, cr[sI]));
          cs[tj] = fmaf(e, izr[sI], cs[tj]);
        }
      }
#pragma unroll
    for (int tj = 0; tj < 8; ++tj) {
      cs[tj] += __shfl_xor(cs[tj], 16);
      cs[tj] += __shfl_xor(cs[tj], 32);
    }
    if (quad == 0) {
#pragma unroll
      for (int tj = 0; tj < 8; ++tj)
        atomicAdd(&colsum[kb + tj * 16 + l15], cs[tj]);
    }
  }
}

// ---------- fp64 re-rank of near-tie candidates (matches np-f64 math exactly) ----------
__global__ __launch_bounds__(64) void k_refine(const float* __restrict__ z,
    const float* __restrict__ emb, const unsigned* __restrict__ candList,
    const unsigned* __restrict__ candCnt, unsigned long long* __restrict__ rowkey) {
  const unsigned cnt = *candCnt;
  const unsigned lim = cnt < CAND_CAP ? cnt : CAND_CAP;
  const unsigned slot = blockIdx.x;
  if (slot >= lim) return;
  const unsigned pr = candList[slot];
  const int n = (int)(pr >> 14), k = (int)(pr & 0x3FFFu);
  const int b = n >> 10, hw = n & 1023;
  const int lane = threadIdx.x;
  double sz = 0.0, se = 0.0, sp = 0.0;
#pragma unroll
  for (int u = 0; u < CDIM / 64; ++u) {
    const int c = lane + u * 64;
    const double zv = (double)z[((size_t)(b * CDIM + c) << 10) + hw];
    const double ev = (double)emb[(size_t)k * CDIM + c];
    sz = fma(zv, zv, sz); se = fma(ev, ev, se); sp = fma(zv, ev, sp);
  }
  for (int off = 32; off; off >>= 1) {
    sz += __shfl_down(sz, off);
    se += __shfl_down(se, off);
    sp += __shfl_down(sp, off);
  }
  if (lane == 0) {
    const double nz = fmax(sqrt(sz), 1e-12);
    const double ne = fmax(sqrt(se), 1e-12);
    const double d = sz / (nz * nz) + se / (ne * ne) - 2.0 * sp / (nz * ne);
    const unsigned long long key =
        (((unsigned long long)(d * 140737488355328.0)) << 14) | (unsigned long long)k;
    atomicMin(&rowkey[n], key);
  }
}

__global__ __launch_bounds__(256) void k_fidx(const unsigned long long* __restrict__ rowkey,
    int* __restrict__ idxI, float* __restrict__ outIdxF) {
  const int n = blockIdx.x * 256 + threadIdx.x;
  const unsigned long long key = rowkey[n];
  const int k = (key != ~0ull) ? (int)(key & 0x3FFFull) : 0;
  idxI[n] = k;
  outIdxF[n] = (float)k;
}

// ---------- z_q gather (reconstruct fp32 from hi+lo) + transpose store + vq sums ----------
__global__ __launch_bounds__(256) void k_zq(const unsigned short* __restrict__ A3,
    const unsigned short* __restrict__ B3, const int* __restrict__ idxI,
    const long long* __restrict__ qids, float* __restrict__ outZ,
    float* __restrict__ scalars) {
  __shared__ float sbuf[4];
  const int n = blockIdx.x, c = threadIdx.x;
  const int bI = idxI[n];
  const float e  = bf2f(B3[(size_t)bI * K3 + c]) + bf2f(B3[(size_t)bI * K3 + CDIM + c]);
  const float zf = bf2f(A3[(size_t)n * K3 + c]) + bf2f(A3[(size_t)n * K3 + 2*CDIM + c]);
  const int b = n >> 10, hw = n & 1023;
  outZ[((size_t)(b * CDIM + c) << 10) + hw] = e;   // [B,C,H,W]
  const float d = e - zf;
  const float ss = blockReduceSum256(d * d, sbuf);
  if (c == 0) {
    const int w = n & 31;
    if ((long long)w <= qids[b]) atomicAdd(&scalars[0], ss * (1.0f / 256.0f));
  }
}

__global__ __launch_bounds__(256) void k_avgent(const float* __restrict__ colsum,
                                                float* __restrict__ scalars) {
  __shared__ float sbuf[4];
  const int i = blockIdx.x * 256 + threadIdx.x;
  const float q = colsum[i] * (1.0f / (float)N_TOK);
  const float c = q * logf(q + 1e-5f);
  const float s = blockReduceSum256(c, sbuf);
  if (threadIdx.x == 0) atomicAdd(&scalars[2], s);
}

__global__ __launch_bounds__(256) void k_final(const int* __restrict__ idxI,
    const long long* __restrict__ qids, const float* __restrict__ scalars,
    float* __restrict__ out) {
  __shared__ float sbuf[4];
  const int tid = threadIdx.x;
  int cnt = 0;
  for (int p = tid; p < 1024; p += 256) {
    const int v = idxI[p];
    bool eq = true;
    for (int b = 1; b < 16; ++b) eq = eq && (idxI[b * 1024 + p] == v);
    cnt += eq ? 1 : 0;
  }
  const float dc = blockReduceSum256((float)cnt, sbuf);
  if (tid == 0) {
    float denom = 0.f;
    for (int b = 0; b < 16; ++b) denom += (float)(qids[b] + 1ll);
    out[4194304] = scalars[0] / denom;
    out[4194305] = 0.25f * scalars[0] / denom;
    out[4194306] = 0.1f * (scalars[1] * (1.0f / (float)N_TOK) + scalars[2]);
    out[4194307] = dc * (1.0f / 1024.0f);
  }
}

extern "C" void kernel_launch(void* const* d_in, const int* in_sizes, int n_in,
                              void* d_out, int out_size, void* d_ws, size_t ws_size,
                              hipStream_t stream) {
  const float*      z    = (const float*)d_in[0];
  const float*      emb  = (const float*)d_in[1];
  const long long*  qids = (const long long*)d_in[2];
  float* out = (float*)d_out;
  float* W   = (float*)d_ws;

  unsigned short* A3 = (unsigned short*)(W + OFF_A3);
  unsigned short* B3 = (unsigned short*)(W + OFF_B3);
  float* ee     = W + OFF_EE;
  float* sM     = W + OFF_SM;
  float* sZ     = W + OFF_SZ;
  float* sE     = W + OFF_SE;
  float* mL     = W + OFF_ML;
  float* invZ   = W + OFF_IZ;
  int*   idxI   = (int*)(W + OFF_IDX);
  float* colsum = W + OFF_CS;
  float* scal   = W + OFF_SC;
  unsigned long long* rowkey = (unsigned long long*)(W + OFF_RK);
  unsigned* candList = (unsigned*)(W + OFF_CL);
  unsigned* candCnt  = (unsigned*)(W + OFF_CC);

  k_zero    <<<dim3(64),          dim3(256), 0, stream>>>(colsum, scal, rowkey, candCnt);
  k_norm_emb<<<dim3(N_E),         dim3(256), 0, stream>>>(emb, B3, ee);
  k_norm_z  <<<dim3(N_TOK),       dim3(256), 0, stream>>>(z, A3);
  k_pass1   <<<dim3(NCH, 128),    dim3(256), 0, stream>>>(A3, B3, ee, sM, sZ, sE);
  k_merge   <<<dim3(N_TOK / 256), dim3(256), 0, stream>>>(sM, sZ, sE, mL, invZ, scal);
  k_pass2   <<<dim3(NCH, 128),    dim3(256), 0, stream>>>(A3, B3, ee, mL, invZ, colsum,
                                                          candList, candCnt);
  k_refine  <<<dim3(CAND_CAP),    dim3(64),  0, stream>>>(z, emb, candList, candCnt, rowkey);
  k_fidx    <<<dim3(N_TOK / 256), dim3(256), 0, stream>>>(rowkey, idxI, out + 4194308);
  k_zq      <<<dim3(N_TOK),       dim3(256), 0, stream>>>(A3, B3, idxI, qids, out, scal);
  k_avgent  <<<dim3(N_E / 256),   dim3(256), 0, stream>>>(colsum, scal);
  k_final   <<<dim3(1),           dim3(256), 0, stream>>>(idxI, qids, scal, out);
}

// Round 5
// 1040.690 us; speedup vs baseline: 4.1569x; 1.9075x over previous
//
#include <hip/hip_runtime.h>
#include <math.h>

// Problem constants
#define N_TOK   16384
#define N_E     16384
#define CDIM    256
#define K2      512              // layout: [hi(256) | lo(256)]; GEMM uses hi only
#define NCH     8
#define CHSZ    (N_E / NCH)      // 2048
#define CT_PER_BLK (CHSZ / 128)  // 16
#define L2E100  144.26950408889634f   // 100 * log2(e)
#define EPS_T   0.005f
#define EPS_X   (-0.7213475f)    // -EPS_T * L2E100
#define CAP_T   65536u
#define CAP_F   32768u

typedef __attribute__((ext_vector_type(8))) short short8;
typedef __attribute__((ext_vector_type(4))) float f32x4;

// ---- workspace layout (float offsets) ----
#define OFF_A2   0u          // ushort[16384*512] = 4194304 floats
#define OFF_B2   4194304u    // ushort[16384*512]
#define OFF_EE   8388608u    // 16384
#define OFF_SM   8404992u    // 8*16384
#define OFF_SZ   8536064u
#define OFF_SE   8667136u
#define OFF_ML   8798208u
#define OFF_IZ   8814592u
#define OFF_IDX  8830976u
#define OFF_CS   8847360u
#define OFF_SC   8863744u    // 16
#define OFF_RK   8863760u    // 16384 u64
#define OFF_CL   8896528u    // 65536 u32
#define OFF_CC   8962064u    // 16
#define OFF_C2   8962080u    // 16384 float2
#define OFF_T    8994848u    // fp16 T[k][n] 16384x16384 = 512 MB (T-path only)
#define NEED_T_BYTES (8994848ull * 4ull + 536870912ull)

__device__ __forceinline__ unsigned short f2bf(float x) {
  unsigned u = __float_as_uint(x);
  unsigned r = (u + 0x7fffu + ((u >> 16) & 1u)) >> 16;
  return (unsigned short)r;
}
__device__ __forceinline__ float bf2f(unsigned short h) {
  return __uint_as_float(((unsigned)h) << 16);
}

__device__ __forceinline__ void async_load16(const void* g, void* l) {
  __builtin_amdgcn_global_load_lds((const __attribute__((address_space(1))) void*)g,
                                   (__attribute__((address_space(3))) void*)l, 16, 0, 0);
}

__device__ __forceinline__ float blockReduceSum256(float v, float* sbuf) {
  __syncthreads();
  v += __shfl_down(v, 32);
  v += __shfl_down(v, 16);
  v += __shfl_down(v, 8);
  v += __shfl_down(v, 4);
  v += __shfl_down(v, 2);
  v += __shfl_down(v, 1);
  const int tid = threadIdx.x;
  if ((tid & 63) == 0) sbuf[tid >> 6] = v;
  __syncthreads();
  return sbuf[0] + sbuf[1] + sbuf[2] + sbuf[3];
}

__global__ __launch_bounds__(256) void k_zero(float* __restrict__ colsum,
                                              float* __restrict__ scalars,
                                              unsigned long long* __restrict__ rowkey,
                                              unsigned* __restrict__ candCnt) {
  const int i = blockIdx.x * 256 + threadIdx.x;
  if (i < N_E)   colsum[i] = 0.f;
  if (i < N_TOK) rowkey[i] = ~0ull;
  if (i < 16)    scalars[i] = 0.f;
  if (i == 0)    *candCnt = 0u;
}

__global__ __launch_bounds__(256) void k_norm_emb(const float* __restrict__ emb,
                                                  unsigned short* __restrict__ B2,
                                                  float* __restrict__ ee) {
  __shared__ float sbuf[4];
  const int k = blockIdx.x, c = threadIdx.x;
  const float x = emb[(size_t)k * CDIM + c];
  const float ss = blockReduceSum256(x * x, sbuf);
  const float y = x / fmaxf(sqrtf(ss), 1e-12f);
  const unsigned short hi = f2bf(y);
  const unsigned short lo = f2bf(y - bf2f(hi));
  B2[(size_t)k * K2 + c]        = hi;
  B2[(size_t)k * K2 + CDIM + c] = lo;
  const float s2 = blockReduceSum256(y * y, sbuf);
  if (c == 0) ee[k] = s2;
}

__global__ __launch_bounds__(256) void k_norm_z(const float* __restrict__ z,
                                                unsigned short* __restrict__ A2) {
  __shared__ float sbuf[4];
  const int n = blockIdx.x, c = threadIdx.x;
  const int b = n >> 10, hw = n & 1023;
  const float x = z[((size_t)(b * CDIM + c) << 10) + hw];
  const float ss = blockReduceSum256(x * x, sbuf);
  const float y = x / fmaxf(sqrtf(ss), 1e-12f);
  const unsigned short hi = f2bf(y);
  const unsigned short lo = f2bf(y - bf2f(hi));
  A2[(size_t)n * K2 + c]        = hi;
  A2[(size_t)n * K2 + CDIM + c] = lo;
}

// ================= pass 1: bf16 MFMA GEMM (hi only, K=256) + online softmax + optional fp16 T store ==========
__global__ __launch_bounds__(256) void k_pass1(const unsigned short* __restrict__ A2,
    const unsigned short* __restrict__ B2, const float* __restrict__ ee,
    float* __restrict__ sM, float* __restrict__ sZ, float* __restrict__ sE,
    _Float16* __restrict__ Tout) {
  __shared__ alignas(16) unsigned short At[128 * 64];
  __shared__ alignas(16) unsigned short Bt[128 * 64];
  const int chunk = blockIdx.x, rt = blockIdx.y;
  const int r0 = rt * 128, k0 = chunk * CHSZ;
  const int tid = threadIdx.x, lane = tid & 63, w = tid >> 6;
  const int wr = w * 32;
  const int l15 = lane & 15, quad = lane >> 4;
  const unsigned ldsbase = (unsigned)(tid & ~63) * 16u;

  float m_[8], Z_[8], E_[8];
#pragma unroll
  for (int i = 0; i < 8; ++i) { m_[i] = -1e30f; Z_[i] = 0.f; E_[i] = 0.f; }

  for (int ct = 0; ct < CT_PER_BLK; ++ct) {
    const int kb = k0 + ct * 128;
    f32x4 acc[2][8];
#pragma unroll
    for (int ti = 0; ti < 2; ++ti)
#pragma unroll
      for (int tj = 0; tj < 8; ++tj) acc[ti][tj] = (f32x4){0.f, 0.f, 0.f, 0.f};
    float eev[8];
#pragma unroll
    for (int tj = 0; tj < 8; ++tj) eev[tj] = ee[kb + tj * 16 + l15];

    for (int s = 0; s < CDIM; s += 64) {
      __syncthreads();
#pragma unroll
      for (int i = 0; i < 4; ++i) {
        const int lin = i * 256 + tid, row = lin >> 3, cg = lin & 7;
        const int gcg = cg ^ (row & 7);
        async_load16((const char*)A2 + ((size_t)(r0 + row) * K2 + s + gcg * 8) * 2,
                     (char*)At + (i * 4096 + ldsbase));
        async_load16((const char*)B2 + ((size_t)(kb + row) * K2 + s + gcg * 8) * 2,
                     (char*)Bt + (i * 4096 + ldsbase));
      }
      __syncthreads();
#pragma unroll
      for (int kk = 0; kk < 2; ++kk) {
        short8 af[2], bfr[8];
#pragma unroll
        for (int ti = 0; ti < 2; ++ti)
          af[ti] = *(const short8*)&At[(wr + ti * 16 + l15) * 64 + (((kk * 4 + quad) ^ (l15 & 7)) * 8)];
#pragma unroll
        for (int tj = 0; tj < 8; ++tj)
          bfr[tj] = *(const short8*)&Bt[(tj * 16 + l15) * 64 + (((kk * 4 + quad) ^ (l15 & 7)) * 8)];
#pragma unroll
        for (int ti = 0; ti < 2; ++ti)
#pragma unroll
          for (int tj = 0; tj < 8; ++tj)
            acc[ti][tj] = __builtin_amdgcn_mfma_f32_16x16x32_bf16(af[ti], bfr[tj], acc[ti][tj], 0, 0, 0);
      }
    }

    // convert acc -> t in place; optionally store fp16 T[k][n] (col-major: lane's 4 rows contiguous)
#pragma unroll
    for (int ti = 0; ti < 2; ++ti)
#pragma unroll
      for (int tj = 0; tj < 8; ++tj) {
        f32x4 a = acc[ti][tj];
#pragma unroll
        for (int r = 0; r < 4; ++r) a[r] = fmaf(2.f, a[r], -eev[tj]);
        acc[ti][tj] = a;
        if (Tout != nullptr) {
          union { uint2 v; _Float16 h[4]; } pk;
#pragma unroll
          for (int r = 0; r < 4; ++r) pk.h[r] = (_Float16)a[r];
          const int col  = kb + tj * 16 + l15;
          const int row0 = r0 + wr + ti * 16 + quad * 4;
          *(uint2*)&Tout[(size_t)col * N_TOK + row0] = pk.v;
        }
      }

    // fused online softmax (t-units; logits = 100*t)
#pragma unroll
    for (int ti = 0; ti < 2; ++ti)
#pragma unroll
      for (int r = 0; r < 4; ++r) {
        const int sI = ti * 4 + r;
        float mt = acc[ti][0][r];
#pragma unroll
        for (int tj = 1; tj < 8; ++tj) mt = fmaxf(mt, acc[ti][tj][r]);
        const float mo = m_[sI];
        const float m2 = fmaxf(mo, mt);
        const float sc = exp2f((mo - m2) * L2E100);
        float Zr = Z_[sI];
        float Er = (E_[sI] - (m2 - mo) * Zr) * sc;
        Zr *= sc;
#pragma unroll
        for (int tj = 0; tj < 8; ++tj) {
          const float d = acc[ti][tj][r] - m2;
          const float e = exp2f(d * L2E100);
          Zr += e;
          Er = fmaf(d, e, Er);
        }
        m_[sI] = m2; Z_[sI] = Zr; E_[sI] = Er;
      }
  }

  // merge the 16 l15-partials (disjoint code subsets, same rows)
#pragma unroll
  for (int sI = 0; sI < 8; ++sI) {
#pragma unroll
    for (int bit = 1; bit < 16; bit <<= 1) {
      const float mo = __shfl_xor(m_[sI], bit);
      const float Zo = __shfl_xor(Z_[sI], bit);
      const float Eo = __shfl_xor(E_[sI], bit);
      const float m2 = fmaxf(m_[sI], mo);
      const float s1 = exp2f((m_[sI] - m2) * L2E100);
      const float s2 = exp2f((mo - m2) * L2E100);
      E_[sI] = (E_[sI] - (m2 - m_[sI]) * Z_[sI]) * s1 + (Eo - (m2 - mo) * Zo) * s2;
      Z_[sI] = Z_[sI] * s1 + Zo * s2;
      m_[sI] = m2;
    }
  }
  if (l15 == 0) {
#pragma unroll
    for (int ti = 0; ti < 2; ++ti)
#pragma unroll
      for (int r = 0; r < 4; ++r) {
        const int gr = r0 + wr + ti * 16 + quad * 4 + r;
        const size_t o = (size_t)chunk * N_TOK + gr;
        sM[o] = m_[ti * 4 + r]; sZ[o] = Z_[ti * 4 + r]; sE[o] = E_[ti * 4 + r];
      }
  }
}

// ---------- merge chunk partials -> final m, 1/Z, packed (c,iz); sample entropy ----------
__global__ __launch_bounds__(256) void k_merge(const float* __restrict__ sM,
    const float* __restrict__ sZ, const float* __restrict__ sE,
    float* __restrict__ mL, float* __restrict__ invZ, float2* __restrict__ C2,
    float* __restrict__ scalars) {
  __shared__ float sbuf[4];
  const int r = blockIdx.x * 256 + threadIdx.x;
  float m = -1e30f, Z = 0.f, E = 0.f;
  for (int c = 0; c < NCH; ++c) {
    const size_t o = (size_t)c * N_TOK + r;
    const float mc = sM[o], Zc = sZ[o], Ec = sE[o];
    const float m2 = fmaxf(m, mc);
    const float s1 = exp2f((m - m2) * L2E100);
    const float s2 = exp2f((mc - m2) * L2E100);
    E = (E - (m2 - m) * Z) * s1 + (Ec - (m2 - mc) * Zc) * s2;
    Z = Z * s1 + Zc * s2;
    m = m2;
  }
  const float iz = 1.0f / Z;
  mL[r] = m; invZ[r] = iz;
  C2[r] = make_float2(-m * L2E100, iz);
  const float ent = logf(Z) - 100.f * E / Z;
  const float s = blockReduceSum256(ent, sbuf);
  if (threadIdx.x == 0) atomicAdd(&scalars[1], s);
}

// ---------- T-path: column sums of probs from stored fp16 T + candidate scan ----------
__global__ __launch_bounds__(256) void k_colsum(const _Float16* __restrict__ T,
    const float2* __restrict__ C2, float* __restrict__ colsum,
    unsigned* __restrict__ candList, unsigned* __restrict__ candCnt) {
  const int tid = threadIdx.x, lane = tid & 63, wv = tid >> 6;
  const int kb0 = blockIdx.x * 16 + wv * 4;      // 4 k per wave, 16 per block
  float acc[4] = {0.f, 0.f, 0.f, 0.f};
  for (int iter = 0; iter < 32; ++iter) {
    const int n0 = iter * 512 + lane * 8;
    uint4 tv[4];
#pragma unroll
    for (int kk = 0; kk < 4; ++kk)
      tv[kk] = *(const uint4*)&T[(size_t)(kb0 + kk) * N_TOK + n0];
    const float4* c4p = (const float4*)(C2 + n0);
    float cc[8], iz[8];
#pragma unroll
    for (int q = 0; q < 4; ++q) {
      const float4 f = c4p[q];
      cc[q * 2]     = f.x; iz[q * 2]     = f.y;
      cc[q * 2 + 1] = f.z; iz[q * 2 + 1] = f.w;
    }
#pragma unroll
    for (int kk = 0; kk < 4; ++kk) {
      const unsigned wbits[4] = {tv[kk].x, tv[kk].y, tv[kk].z, tv[kk].w};
#pragma unroll
      for (int u = 0; u < 8; ++u) {
        union { unsigned short us; _Float16 h; } cvt;
        cvt.us = (unsigned short)((wbits[u >> 1] >> ((u & 1) * 16)) & 0xffffu);
        const float t = (float)cvt.h;
        const float x = fmaf(t, L2E100, cc[u]);
        acc[kk] = fmaf(exp2f(x), iz[u], acc[kk]);
        if (x >= EPS_X) {
          const unsigned slot = atomicAdd(candCnt, 1u);
          if (slot < CAP_T)
            candList[slot] = ((unsigned)(n0 + u) << 14) | (unsigned)(kb0 + kk);
        }
      }
    }
  }
#pragma unroll
  for (int kk = 0; kk < 4; ++kk) {
    acc[kk] += __shfl_down(acc[kk], 32);
    acc[kk] += __shfl_down(acc[kk], 16);
    acc[kk] += __shfl_down(acc[kk], 8);
    acc[kk] += __shfl_down(acc[kk], 4);
    acc[kk] += __shfl_down(acc[kk], 2);
    acc[kk] += __shfl_down(acc[kk], 1);
    if (lane == 0) colsum[kb0 + kk] = acc[kk];
  }
}

// ---------- fallback pass 2: recompute GEMM, colsums via atomics, candidates ----------
__global__ __launch_bounds__(256) void k_pass2(const unsigned short* __restrict__ A2,
    const unsigned short* __restrict__ B2, const float* __restrict__ ee,
    const float* __restrict__ mL, const float* __restrict__ invZ,
    float* __restrict__ colsum, unsigned* __restrict__ candList,
    unsigned* __restrict__ candCnt) {
  __shared__ alignas(16) unsigned short At[128 * 64];
  __shared__ alignas(16) unsigned short Bt[128 * 64];
  const int chunk = blockIdx.x, rt = blockIdx.y;
  const int r0 = rt * 128, k0 = chunk * CHSZ;
  const int tid = threadIdx.x, lane = tid & 63, w = tid >> 6;
  const int wr = w * 32;
  const int l15 = lane & 15, quad = lane >> 4;
  const unsigned ldsbase = (unsigned)(tid & ~63) * 16u;

  float mr[8], izr[8], cr[8];
#pragma unroll
  for (int ti = 0; ti < 2; ++ti)
#pragma unroll
    for (int r = 0; r < 4; ++r) {
      const int gr = r0 + wr + ti * 16 + quad * 4 + r;
      mr[ti * 4 + r]  = mL[gr];
      izr[ti * 4 + r] = invZ[gr];
      cr[ti * 4 + r]  = -mL[gr] * L2E100;
    }

  for (int ct = 0; ct < CT_PER_BLK; ++ct) {
    const int kb = k0 + ct * 128;
    f32x4 acc[2][8];
#pragma unroll
    for (int ti = 0; ti < 2; ++ti)
#pragma unroll
      for (int tj = 0; tj < 8; ++tj) acc[ti][tj] = (f32x4){0.f, 0.f, 0.f, 0.f};
    float eev[8];
#pragma unroll
    for (int tj = 0; tj < 8; ++tj) eev[tj] = ee[kb + tj * 16 + l15];

    for (int s = 0; s < CDIM; s += 64) {
      __syncthreads();
#pragma unroll
      for (int i = 0; i < 4; ++i) {
        const int lin = i * 256 + tid, row = lin >> 3, cg = lin & 7;
        const int gcg = cg ^ (row & 7);
        async_load16((const char*)A2 + ((size_t)(r0 + row) * K2 + s + gcg * 8) * 2,
                     (char*)At + (i * 4096 + ldsbase));
        async_load16((const char*)B2 + ((size_t)(kb + row) * K2 + s + gcg * 8) * 2,
                     (char*)Bt + (i * 4096 + ldsbase));
      }
      __syncthreads();
#pragma unroll
      for (int kk = 0; kk < 2; ++kk) {
        short8 af[2], bfr[8];
#pragma unroll
        for (int ti = 0; ti < 2; ++ti)
          af[ti] = *(const short8*)&At[(wr + ti * 16 + l15) * 64 + (((kk * 4 + quad) ^ (l15 & 7)) * 8)];
#pragma unroll
        for (int tj = 0; tj < 8; ++tj)
          bfr[tj] = *(const short8*)&Bt[(tj * 16 + l15) * 64 + (((kk * 4 + quad) ^ (l15 & 7)) * 8)];
#pragma unroll
        for (int ti = 0; ti < 2; ++ti)
#pragma unroll
          for (int tj = 0; tj < 8; ++tj)
            acc[ti][tj] = __builtin_amdgcn_mfma_f32_16x16x32_bf16(af[ti], bfr[tj], acc[ti][tj], 0, 0, 0);
      }
    }

    float cs[8];
#pragma unroll
    for (int tj = 0; tj < 8; ++tj) cs[tj] = 0.f;
#pragma unroll
    for (int ti = 0; ti < 2; ++ti)
#pragma unroll
      for (int r = 0; r < 4; ++r) {
        const int sI = ti * 4 + r;
#pragma unroll
        for (int tj = 0; tj < 8; ++tj) {
          const float t = fmaf(2.f, acc[ti][tj][r], -eev[tj]);
          if (t >= mr[sI] - EPS_T) {
            const unsigned slot = atomicAdd(candCnt, 1u);
            if (slot < CAP_F) {
              const unsigned row = (unsigned)(r0 + wr + ti * 16 + quad * 4 + r);
              const unsigned col = (unsigned)(kb + tj * 16 + l15);
              candList[slot] = (row << 14) | col;
            }
          }
          const float e = exp2f(fmaf(t, L2E100, cr[sI]));
          cs[tj] = fmaf(e, izr[sI], cs[tj]);
        }
      }
#pragma unroll
    for (int tj = 0; tj < 8; ++tj) {
      cs[tj] += __shfl_xor(cs[tj], 16);
      cs[tj] += __shfl_xor(cs[tj], 32);
    }
    if (quad == 0) {
#pragma unroll
      for (int tj = 0; tj < 8; ++tj)
        atomicAdd(&colsum[kb + tj * 16 + l15], cs[tj]);
    }
  }
}

// ---------- fp64 re-rank of near-tie candidates (persistent-strided) ----------
__global__ __launch_bounds__(256) void k_refine(const float* __restrict__ z,
    const float* __restrict__ emb, const unsigned* __restrict__ candList,
    const unsigned* __restrict__ candCnt, unsigned long long* __restrict__ rowkey,
    unsigned cap) {
  const unsigned cnt = *candCnt;
  const unsigned lim = cnt < cap ? cnt : cap;
  const int lane = threadIdx.x & 63, wv = threadIdx.x >> 6;
  for (unsigned slot = blockIdx.x * 4 + wv; slot < lim; slot += gridDim.x * 4) {
    const unsigned pr = candList[slot];
    const int n = (int)(pr >> 14), k = (int)(pr & 0x3FFFu);
    const int b = n >> 10, hw = n & 1023;
    double sz = 0.0, se = 0.0, sp = 0.0;
#pragma unroll
    for (int u = 0; u < CDIM / 64; ++u) {
      const int c = lane + u * 64;
      const double zv = (double)z[((size_t)(b * CDIM + c) << 10) + hw];
      const double ev = (double)emb[(size_t)k * CDIM + c];
      sz = fma(zv, zv, sz); se = fma(ev, ev, se); sp = fma(zv, ev, sp);
    }
    for (int off = 32; off; off >>= 1) {
      sz += __shfl_down(sz, off);
      se += __shfl_down(se, off);
      sp += __shfl_down(sp, off);
    }
    if (lane == 0) {
      const double nz = fmax(sqrt(sz), 1e-12);
      const double ne = fmax(sqrt(se), 1e-12);
      const double d = sz / (nz * nz) + se / (ne * ne) - 2.0 * sp / (nz * ne);
      const unsigned long long key =
          (((unsigned long long)(d * 140737488355328.0)) << 14) | (unsigned long long)k;
      atomicMin(&rowkey[n], key);
    }
  }
}

__global__ __launch_bounds__(256) void k_fidx(const unsigned long long* __restrict__ rowkey,
    int* __restrict__ idxI, float* __restrict__ outIdxF) {
  const int n = blockIdx.x * 256 + threadIdx.x;
  const unsigned long long key = rowkey[n];
  const int k = (key != ~0ull) ? (int)(key & 0x3FFFull) : 0;
  idxI[n] = k;
  outIdxF[n] = (float)k;
}

// ---------- z_q gather (hi+lo reconstruction) + transpose store + vq sums ----------
__global__ __launch_bounds__(256) void k_zq(const unsigned short* __restrict__ A2,
    const unsigned short* __restrict__ B2, const int* __restrict__ idxI,
    const long long* __restrict__ qids, float* __restrict__ outZ,
    float* __restrict__ scalars) {
  __shared__ float sbuf[4];
  const int n = blockIdx.x, c = threadIdx.x;
  const int bI = idxI[n];
  const float e  = bf2f(B2[(size_t)bI * K2 + c]) + bf2f(B2[(size_t)bI * K2 + CDIM + c]);
  const float zf = bf2f(A2[(size_t)n * K2 + c]) + bf2f(A2[(size_t)n * K2 + CDIM + c]);
  const int b = n >> 10, hw = n & 1023;
  outZ[((size_t)(b * CDIM + c) << 10) + hw] = e;
  const float d = e - zf;
  const float ss = blockReduceSum256(d * d, sbuf);
  if (c == 0) {
    const int w = n & 31;
    if ((long long)w <= qids[b]) atomicAdd(&scalars[0], ss * (1.0f / 256.0f));
  }
}

__global__ __launch_bounds__(256) void k_avgent(const float* __restrict__ colsum,
                                                float* __restrict__ scalars) {
  __shared__ float sbuf[4];
  const int i = blockIdx.x * 256 + threadIdx.x;
  const float q = colsum[i] * (1.0f / (float)N_TOK);
  const float c = q * logf(q + 1e-5f);
  const float s = blockReduceSum256(c, sbuf);
  if (threadIdx.x == 0) atomicAdd(&scalars[2], s);
}

__global__ __launch_bounds__(256) void k_final(const int* __restrict__ idxI,
    const long long* __restrict__ qids, const float* __restrict__ scalars,
    float* __restrict__ out) {
  __shared__ float sbuf[4];
  const int tid = threadIdx.x;
  int cnt = 0;
  for (int p = tid; p < 1024; p += 256) {
    const int v = idxI[p];
    bool eq = true;
    for (int b = 1; b < 16; ++b) eq = eq && (idxI[b * 1024 + p] == v);
    cnt += eq ? 1 : 0;
  }
  const float dc = blockReduceSum256((float)cnt, sbuf);
  if (tid == 0) {
    float denom = 0.f;
    for (int b = 0; b < 16; ++b) denom += (float)(qids[b] + 1ll);
    out[4194304] = scalars[0] / denom;
    out[4194305] = 0.25f * scalars[0] / denom;
    out[4194306] = 0.1f * (scalars[1] * (1.0f / (float)N_TOK) + scalars[2]);
    out[4194307] = dc * (1.0f / 1024.0f);
  }
}

extern "C" void kernel_launch(void* const* d_in, const int* in_sizes, int n_in,
                              void* d_out, int out_size, void* d_ws, size_t ws_size,
                              hipStream_t stream) {
  const float*      z    = (const float*)d_in[0];
  const float*      emb  = (const float*)d_in[1];
  const long long*  qids = (const long long*)d_in[2];
  float* out = (float*)d_out;
  float* W   = (float*)d_ws;

  unsigned short* A2 = (unsigned short*)(W + OFF_A2);
  unsigned short* B2 = (unsigned short*)(W + OFF_B2);
  float* ee     = W + OFF_EE;
  float* sM     = W + OFF_SM;
  float* sZ     = W + OFF_SZ;
  float* sE     = W + OFF_SE;
  float* mL     = W + OFF_ML;
  float* invZ   = W + OFF_IZ;
  int*   idxI   = (int*)(W + OFF_IDX);
  float* colsum = W + OFF_CS;
  float* scal   = W + OFF_SC;
  unsigned long long* rowkey = (unsigned long long*)(W + OFF_RK);
  unsigned* candList = (unsigned*)(W + OFF_CL);
  unsigned* candCnt  = (unsigned*)(W + OFF_CC);
  float2* C2 = (float2*)(W + OFF_C2);
  _Float16* T = (_Float16*)(W + OFF_T);

  const bool tpath = (ws_size >= NEED_T_BYTES);

  k_zero    <<<dim3(64),          dim3(256), 0, stream>>>(colsum, scal, rowkey, candCnt);
  k_norm_emb<<<dim3(N_E),         dim3(256), 0, stream>>>(emb, B2, ee);
  k_norm_z  <<<dim3(N_TOK),       dim3(256), 0, stream>>>(z, A2);
  k_pass1   <<<dim3(NCH, 128),    dim3(256), 0, stream>>>(A2, B2, ee, sM, sZ, sE,
                                                          tpath ? T : (_Float16*)nullptr);
  k_merge   <<<dim3(N_TOK / 256), dim3(256), 0, stream>>>(sM, sZ, sE, mL, invZ, C2, scal);
  if (tpath) {
    k_colsum<<<dim3(N_E / 16),    dim3(256), 0, stream>>>(T, C2, colsum, candList, candCnt);
    k_refine<<<dim3(1024),        dim3(256), 0, stream>>>(z, emb, candList, candCnt, rowkey, CAP_T);
  } else {
    k_pass2 <<<dim3(NCH, 128),    dim3(256), 0, stream>>>(A2, B2, ee, mL, invZ, colsum,
                                                          candList, candCnt);
    k_refine<<<dim3(1024),        dim3(256), 0, stream>>>(z, emb, candList, candCnt, rowkey, CAP_F);
  }
  k_fidx    <<<dim3(N_TOK / 256), dim3(256), 0, stream>>>(rowkey, idxI, out + 4194308);
  k_zq      <<<dim3(N_TOK),       dim3(256), 0, stream>>>(A2, B2, idxI, qids, out, scal);
  k_avgent  <<<dim3(N_E / 256),   dim3(256), 0, stream>>>(colsum, scal);
  k_final   <<<dim3(1),           dim3(256), 0, stream>>>(idxI, qids, scal, out);
}

// Round 6
// 958.338 us; speedup vs baseline: 4.5141x; 1.0859x over previous
//
#include <hip/hip_runtime.h>
#include <math.h>

// Problem constants
#define N_TOK   16384
#define N_E     16384
#define CDIM    256
#define NCH     8
#define CHSZ    (N_E / NCH)      // 2048 codes per chunk
#define L2E100  144.26950408889634f   // 100 * log2(e)
#define DELTA_C 0.06f            // colsum candidate window (below running row max)
#define EPS_NT  0.008f           // near-tie window for fp64 argmin re-rank
#define CAP_BLK 1536u            // per-block candidate cap (E~580, 15 sigma)
#define NT_CAP  65536u
#define NBLK    2048             // pass1 grid = 8 chunks x 256 row-tiles

typedef __attribute__((ext_vector_type(8))) short short8;
typedef __attribute__((ext_vector_type(4))) float f32x4;

// ---- workspace layout (float offsets), total ~44.3 MB (proven ws >= 52.5 MB) ----
#define OFF_A2   0u          // ushort[16384*256] bf16-hi of normalized z (token-major)
#define OFF_B2   2097152u    // ushort[16384*256] bf16-hi of normalized emb
#define OFF_EE   4194304u    // 16384 ||emb_k||^2 (post-norm, fp32)
#define OFF_SM   4210688u    // 8 x 16384 chunk softmax partials
#define OFF_SZ   4341760u
#define OFF_SE   4472832u
#define OFF_ML   4603904u    // 16384 final row max (t-units)
#define OFF_IDX  4620288u    // 16384 int
#define OFF_CS   4636672u    // 16384 colsum
#define OFF_SC   4653056u    // 16 scalars
#define OFF_C2   4653072u    // 16384 float2 {-m*L2E100, invZ} (8B aligned)
#define OFF_RK   4685840u    // 16384 u64 rowkey (8B aligned)
#define OFF_NT   4718608u    // 65536 u32 near-tie list
#define OFF_NTC  4784144u    // counter
#define OFF_CBC  4784160u    // 2048 per-block candidate counts
#define OFF_CAND 4786208u    // u64[2048*1536] {f32 t | row<<14|col} (8B aligned)

__device__ __forceinline__ unsigned short f2bf(float x) {
  unsigned u = __float_as_uint(x);
  unsigned r = (u + 0x7fffu + ((u >> 16) & 1u)) >> 16;
  return (unsigned short)r;
}
__device__ __forceinline__ float bf2f(unsigned short h) {
  return __uint_as_float(((unsigned)h) << 16);
}

__device__ __forceinline__ void async_load16(const void* g, void* l) {
  __builtin_amdgcn_global_load_lds((const __attribute__((address_space(1))) void*)g,
                                   (__attribute__((address_space(3))) void*)l, 16, 0, 0);
}

__device__ __forceinline__ float blockReduceSum256(float v, float* sbuf) {
  __syncthreads();
  v += __shfl_down(v, 32);
  v += __shfl_down(v, 16);
  v += __shfl_down(v, 8);
  v += __shfl_down(v, 4);
  v += __shfl_down(v, 2);
  v += __shfl_down(v, 1);
  const int tid = threadIdx.x;
  if ((tid & 63) == 0) sbuf[tid >> 6] = v;
  __syncthreads();
  return sbuf[0] + sbuf[1] + sbuf[2] + sbuf[3];
}

__global__ __launch_bounds__(256) void k_zero(float* __restrict__ colsum,
                                              float* __restrict__ scalars,
                                              unsigned long long* __restrict__ rowkey,
                                              unsigned* __restrict__ ntc) {
  const int i = blockIdx.x * 256 + threadIdx.x;
  if (i < N_E)   colsum[i] = 0.f;
  if (i < N_TOK) rowkey[i] = ~0ull;
  if (i < 16)    scalars[i] = 0.f;
  if (i == 0)    *ntc = 0u;
}

__global__ __launch_bounds__(256) void k_norm_emb(const float* __restrict__ emb,
                                                  unsigned short* __restrict__ B2,
                                                  float* __restrict__ ee) {
  __shared__ float sbuf[4];
  const int k = blockIdx.x, c = threadIdx.x;
  const float x = emb[(size_t)k * CDIM + c];
  const float ss = blockReduceSum256(x * x, sbuf);
  const float y = x / fmaxf(sqrtf(ss), 1e-12f);
  B2[(size_t)k * CDIM + c] = f2bf(y);
  const float s2 = blockReduceSum256(y * y, sbuf);
  if (c == 0) ee[k] = s2;
}

__global__ __launch_bounds__(256) void k_norm_z(const float* __restrict__ z,
                                                unsigned short* __restrict__ A2) {
  __shared__ float sbuf[4];
  const int n = blockIdx.x, c = threadIdx.x;
  const int b = n >> 10, hw = n & 1023;
  const float x = z[((size_t)(b * CDIM + c) << 10) + hw];
  const float ss = blockReduceSum256(x * x, sbuf);
  A2[(size_t)n * CDIM + c] = f2bf(x / fmaxf(sqrtf(ss), 1e-12f));
}

// ============ pass 1: A-resident, B-double-buffered bf16 MFMA GEMM ============
// + online softmax (m,Z,E) + candidate collection (t >= shared running max - DELTA_C)
__global__ __launch_bounds__(256, 2) void k_pass1(const unsigned short* __restrict__ A2,
    const unsigned short* __restrict__ B2, const float* __restrict__ ee,
    float* __restrict__ sM, float* __restrict__ sZ, float* __restrict__ sE,
    unsigned long long* __restrict__ cand, unsigned* __restrict__ cbc) {
  __shared__ alignas(16) unsigned short Af[64 * 256];     // 32 KB, full-K A tile
  __shared__ alignas(16) unsigned short Bt[2][128 * 64];  // 2 x 16 KB, B double buffer
  __shared__ unsigned lcnt;
  const int chunk = blockIdx.x, rt = blockIdx.y;
  const int r0 = rt * 64, k0 = chunk * CHSZ;
  const int blin = rt * NCH + chunk;
  const int tid = threadIdx.x, lane = tid & 63, w = tid >> 6;
  const int wr = w * 16;
  const int l15 = lane & 15, quad = lane >> 4;

  if (tid == 0) lcnt = 0u;

  // stage full A tile (swizzled 16B groups: g' = g ^ (row&7))
#pragma unroll
  for (int i = 0; i < 8; ++i) {
    const int lin = i * 256 + tid;
    const int row = lin >> 5, cg = lin & 31;
    const int gcg = cg ^ (row & 7);
    async_load16((const char*)A2 + ((size_t)(r0 + row) * CDIM + gcg * 8) * 2,
                 (char*)Af + lin * 16);
  }
  // prefetch B stage 0 into buf 0
#pragma unroll
  for (int i = 0; i < 4; ++i) {
    const int lin = i * 256 + tid;
    const int row = lin >> 3, cg = lin & 7;
    const int gcg = cg ^ (row & 7);
    async_load16((const char*)B2 + ((size_t)(k0 + row) * CDIM + gcg * 8) * 2,
                 (char*)Bt[0] + lin * 16);
  }
  __syncthreads();

  float m_[4], Z_[4], E_[4];
#pragma unroll
  for (int r = 0; r < 4; ++r) { m_[r] = -1e30f; Z_[r] = 0.f; E_[r] = 0.f; }

  f32x4 acc[8];
  float eev[8];
  const int ar = wr + l15;

  for (int g = 0; g < 64; ++g) {           // 16 code-tiles x 4 k-stages
    const int ct = g >> 2, sg = (g & 3) * 64;
    const int kb = k0 + ct * 128;
    if ((g & 3) == 0) {
#pragma unroll
      for (int tj = 0; tj < 8; ++tj) acc[tj] = (f32x4){0.f, 0.f, 0.f, 0.f};
#pragma unroll
      for (int tj = 0; tj < 8; ++tj) eev[tj] = ee[kb + tj * 16 + l15];
    }
    // prefetch next stage into the other buffer (drained at the barrier below)
    if (g < 63) {
      const int gn = g + 1;
      const int kbn = k0 + (gn >> 2) * 128, sn = (gn & 3) * 64;
      unsigned short* dst = (unsigned short*)Bt[gn & 1];
#pragma unroll
      for (int i = 0; i < 4; ++i) {
        const int lin = i * 256 + tid;
        const int row = lin >> 3, cg = lin & 7;
        const int gcg = cg ^ (row & 7);
        async_load16((const char*)B2 + ((size_t)(kbn + row) * CDIM + sn + gcg * 8) * 2,
                     (char*)dst + lin * 16);
      }
    }
    // compute on current buffer
    const unsigned short* bp = Bt[g & 1];
#pragma unroll
    for (int kk = 0; kk < 2; ++kk) {
      const int ga = (sg >> 3) + kk * 4 + quad;
      const short8 af = *(const short8*)&Af[ar * 256 + ((ga ^ (ar & 7)) * 8)];
      short8 bfr[8];
#pragma unroll
      for (int tj = 0; tj < 8; ++tj) {
        const int br = tj * 16 + l15;
        bfr[tj] = *(const short8*)&bp[br * 64 + (((kk * 4 + quad) ^ (br & 7)) * 8)];
      }
#pragma unroll
      for (int tj = 0; tj < 8; ++tj)
        acc[tj] = __builtin_amdgcn_mfma_f32_16x16x32_bf16(af, bfr[tj], acc[tj], 0, 0, 0);
    }
    // per code-tile epilogue: shared running max, online softmax, candidates
    if ((g & 3) == 3) {
#pragma unroll
      for (int r = 0; r < 4; ++r) {
        float tv[8];
#pragma unroll
        for (int tj = 0; tj < 8; ++tj) tv[tj] = fmaf(2.f, acc[tj][r], -eev[tj]);
        float mt = tv[0];
#pragma unroll
        for (int tj = 1; tj < 8; ++tj) mt = fmaxf(mt, tv[tj]);
#pragma unroll
        for (int bit = 1; bit < 16; bit <<= 1) mt = fmaxf(mt, __shfl_xor(mt, bit));
        const float mo = m_[r];
        const float m2 = fmaxf(mo, mt);           // shared across the row's 16 lanes
        const float sc = exp2f((mo - m2) * L2E100);
        float Zr = Z_[r];
        float Er = (E_[r] - (m2 - mo) * Zr) * sc;
        Zr *= sc;
#pragma unroll
        for (int tj = 0; tj < 8; ++tj) {
          const float d = tv[tj] - m2;
          const float e = exp2f(d * L2E100);
          Zr += e;
          Er = fmaf(d, e, Er);
        }
        m_[r] = m2; Z_[r] = Zr; E_[r] = Er;
        const unsigned rowg = (unsigned)(r0 + wr + quad * 4 + r);
#pragma unroll
        for (int tj = 0; tj < 8; ++tj) {
          if (tv[tj] >= m2 - DELTA_C) {
            const unsigned slot = atomicAdd(&lcnt, 1u);
            if (slot < CAP_BLK) {
              const unsigned pr = (rowg << 14) | (unsigned)(kb + tj * 16 + l15);
              cand[(size_t)blin * CAP_BLK + slot] =
                  ((unsigned long long)__float_as_uint(tv[tj]) << 32) | pr;
            }
          }
        }
      }
    }
    __syncthreads();
  }

  // merge the 16 l15-partials (disjoint code subsets, same rows)
#pragma unroll
  for (int r = 0; r < 4; ++r) {
#pragma unroll
    for (int bit = 1; bit < 16; bit <<= 1) {
      const float mo = __shfl_xor(m_[r], bit);
      const float Zo = __shfl_xor(Z_[r], bit);
      const float Eo = __shfl_xor(E_[r], bit);
      const float m2 = fmaxf(m_[r], mo);
      const float s1 = exp2f((m_[r] - m2) * L2E100);
      const float s2 = exp2f((mo - m2) * L2E100);
      E_[r] = (E_[r] - (m2 - m_[r]) * Z_[r]) * s1 + (Eo - (m2 - mo) * Zo) * s2;
      Z_[r] = Z_[r] * s1 + Zo * s2;
      m_[r] = m2;
    }
  }
  if (l15 == 0) {
#pragma unroll
    for (int r = 0; r < 4; ++r) {
      const int gr = r0 + wr + quad * 4 + r;
      const size_t o = (size_t)chunk * N_TOK + gr;
      sM[o] = m_[r]; sZ[o] = Z_[r]; sE[o] = E_[r];
    }
  }
  if (tid == 0) cbc[blin] = lcnt < CAP_BLK ? lcnt : CAP_BLK;
}

// ---------- merge chunk partials -> final m, {c,invZ}; sample entropy ----------
__global__ __launch_bounds__(256) void k_merge(const float* __restrict__ sM,
    const float* __restrict__ sZ, const float* __restrict__ sE,
    float* __restrict__ mL, float2* __restrict__ C2, float* __restrict__ scalars) {
  __shared__ float sbuf[4];
  const int r = blockIdx.x * 256 + threadIdx.x;
  float m = -1e30f, Z = 0.f, E = 0.f;
  for (int c = 0; c < NCH; ++c) {
    const size_t o = (size_t)c * N_TOK + r;
    const float mc = sM[o], Zc = sZ[o], Ec = sE[o];
    const float m2 = fmaxf(m, mc);
    const float s1 = exp2f((m - m2) * L2E100);
    const float s2 = exp2f((mc - m2) * L2E100);
    E = (E - (m2 - m) * Z) * s1 + (Ec - (m2 - mc) * Zc) * s2;
    Z = Z * s1 + Zc * s2;
    m = m2;
  }
  mL[r] = m;
  C2[r] = make_float2(-m * L2E100, 1.0f / Z);
  const float ent = logf(Z) - 100.f * E / Z;
  const float s = blockReduceSum256(ent, sbuf);
  if (threadIdx.x == 0) atomicAdd(&scalars[1], s);
}

// ---------- scatter: colsum from candidates + near-tie filter -> refine list ----------
__global__ __launch_bounds__(256) void k_scatter(const unsigned long long* __restrict__ cand,
    const unsigned* __restrict__ cbc, const float2* __restrict__ C2,
    const float* __restrict__ mL, float* __restrict__ colsum,
    unsigned* __restrict__ ntList, unsigned* __restrict__ ntc) {
  const int b = blockIdx.x;
  const unsigned c0 = cbc[b];
  const unsigned cnt = c0 < CAP_BLK ? c0 : CAP_BLK;
  const int tid = threadIdx.x, lane = tid & 63;
  const unsigned lim = (cnt + 255u) & ~255u;
  for (unsigned i = tid; i < lim; i += 256u) {
    const bool act = i < cnt;
    bool nt = false;
    unsigned pr = 0u;
    if (act) {
      const unsigned long long e = cand[(size_t)b * CAP_BLK + i];
      pr = (unsigned)(e & 0xFFFFFFFu);
      const float t = __uint_as_float((unsigned)(e >> 32));
      const int n = (int)(pr >> 14), col = (int)(pr & 0x3FFFu);
      const float2 c2 = C2[n];
      atomicAdd(&colsum[col], exp2f(fmaf(t, L2E100, c2.x)) * c2.y);
      nt = (t >= mL[n] - EPS_NT);
    }
    const unsigned long long mask = __ballot(nt);
    const unsigned cw = (unsigned)__popcll(mask);
    unsigned base = 0u;
    if (lane == 0 && cw) base = atomicAdd(ntc, cw);
    base = __shfl((int)base, 0);
    if (nt) {
      const unsigned off = (unsigned)__popcll(mask & ((1ull << lane) - 1ull));
      const unsigned s = base + off;
      if (s < NT_CAP) ntList[s] = pr;
    }
  }
}

// ---------- fp64 re-rank of near-tie candidates (matches np-f64 math) ----------
__global__ __launch_bounds__(256) void k_refine(const float* __restrict__ z,
    const float* __restrict__ emb, const unsigned* __restrict__ ntList,
    const unsigned* __restrict__ ntc, unsigned long long* __restrict__ rowkey) {
  const unsigned cnt = *ntc;
  const unsigned lim = cnt < NT_CAP ? cnt : NT_CAP;
  const int lane = threadIdx.x & 63, wv = threadIdx.x >> 6;
  for (unsigned slot = blockIdx.x * 4 + wv; slot < lim; slot += gridDim.x * 4) {
    const unsigned pr = ntList[slot];
    const int n = (int)(pr >> 14), k = (int)(pr & 0x3FFFu);
    const int b = n >> 10, hw = n & 1023;
    double sz = 0.0, se = 0.0, sp = 0.0;
#pragma unroll
    for (int u = 0; u < CDIM / 64; ++u) {
      const int c = lane + u * 64;
      const double zv = (double)z[((size_t)(b * CDIM + c) << 10) + hw];
      const double ev = (double)emb[(size_t)k * CDIM + c];
      sz = fma(zv, zv, sz); se = fma(ev, ev, se); sp = fma(zv, ev, sp);
    }
    for (int off = 32; off; off >>= 1) {
      sz += __shfl_down(sz, off);
      se += __shfl_down(se, off);
      sp += __shfl_down(sp, off);
    }
    if (lane == 0) {
      const double nz = fmax(sqrt(sz), 1e-12);
      const double ne = fmax(sqrt(se), 1e-12);
      const double d = sz / (nz * nz) + se / (ne * ne) - 2.0 * sp / (nz * ne);
      const unsigned long long key =
          (((unsigned long long)(d * 140737488355328.0)) << 14) | (unsigned long long)k;
      atomicMin(&rowkey[n], key);
    }
  }
}

__global__ __launch_bounds__(256) void k_fidx(const unsigned long long* __restrict__ rowkey,
    int* __restrict__ idxI, float* __restrict__ outIdxF) {
  const int n = blockIdx.x * 256 + threadIdx.x;
  const unsigned long long key = rowkey[n];
  const int k = (key != ~0ull) ? (int)(key & 0x3FFFull) : 0;
  idxI[n] = k;
  outIdxF[n] = (float)k;
}

// ---------- z_q gather + transpose store + masked vq sums ----------
__global__ __launch_bounds__(256) void k_zq(const unsigned short* __restrict__ A2,
    const unsigned short* __restrict__ B2, const int* __restrict__ idxI,
    const long long* __restrict__ qids, float* __restrict__ outZ,
    float* __restrict__ scalars) {
  __shared__ float sbuf[4];
  const int n = blockIdx.x, c = threadIdx.x;
  const int bI = idxI[n];
  const float e  = bf2f(B2[(size_t)bI * CDIM + c]);
  const float zf = bf2f(A2[(size_t)n * CDIM + c]);
  const int b = n >> 10, hw = n & 1023;
  outZ[((size_t)(b * CDIM + c) << 10) + hw] = e;
  const float d = e - zf;
  const float ss = blockReduceSum256(d * d, sbuf);
  if (c == 0) {
    const int w = n & 31;
    if ((long long)w <= qids[b]) atomicAdd(&scalars[0], ss * (1.0f / 256.0f));
  }
}

__global__ __launch_bounds__(256) void k_avgent(const float* __restrict__ colsum,
                                                float* __restrict__ scalars) {
  __shared__ float sbuf[4];
  const int i = blockIdx.x * 256 + threadIdx.x;
  const float q = colsum[i] * (1.0f / (float)N_TOK);
  const float c = q * logf(q + 1e-5f);
  const float s = blockReduceSum256(c, sbuf);
  if (threadIdx.x == 0) atomicAdd(&scalars[2], s);
}

__global__ __launch_bounds__(256) void k_final(const int* __restrict__ idxI,
    const long long* __restrict__ qids, const float* __restrict__ scalars,
    float* __restrict__ out) {
  __shared__ float sbuf[4];
  const int tid = threadIdx.x;
  int cnt = 0;
  for (int p = tid; p < 1024; p += 256) {
    const int v = idxI[p];
    bool eq = true;
    for (int b = 1; b < 16; ++b) eq = eq && (idxI[b * 1024 + p] == v);
    cnt += eq ? 1 : 0;
  }
  const float dc = blockReduceSum256((float)cnt, sbuf);
  if (tid == 0) {
    float denom = 0.f;
    for (int b = 0; b < 16; ++b) denom += (float)(qids[b] + 1ll);
    out[4194304] = scalars[0] / denom;
    out[4194305] = 0.25f * scalars[0] / denom;
    out[4194306] = 0.1f * (scalars[1] * (1.0f / (float)N_TOK) + scalars[2]);
    out[4194307] = dc * (1.0f / 1024.0f);
  }
}

extern "C" void kernel_launch(void* const* d_in, const int* in_sizes, int n_in,
                              void* d_out, int out_size, void* d_ws, size_t ws_size,
                              hipStream_t stream) {
  const float*      z    = (const float*)d_in[0];
  const float*      emb  = (const float*)d_in[1];
  const long long*  qids = (const long long*)d_in[2];
  float* out = (float*)d_out;
  float* W   = (float*)d_ws;

  unsigned short* A2 = (unsigned short*)(W + OFF_A2);
  unsigned short* B2 = (unsigned short*)(W + OFF_B2);
  float* ee     = W + OFF_EE;
  float* sM     = W + OFF_SM;
  float* sZ     = W + OFF_SZ;
  float* sE     = W + OFF_SE;
  float* mL     = W + OFF_ML;
  int*   idxI   = (int*)(W + OFF_IDX);
  float* colsum = W + OFF_CS;
  float* scal   = W + OFF_SC;
  float2* C2    = (float2*)(W + OFF_C2);
  unsigned long long* rowkey = (unsigned long long*)(W + OFF_RK);
  unsigned* ntList = (unsigned*)(W + OFF_NT);
  unsigned* ntc    = (unsigned*)(W + OFF_NTC);
  unsigned* cbc    = (unsigned*)(W + OFF_CBC);
  unsigned long long* cand = (unsigned long long*)(W + OFF_CAND);

  k_zero    <<<dim3(64),          dim3(256), 0, stream>>>(colsum, scal, rowkey, ntc);
  k_norm_emb<<<dim3(N_E),         dim3(256), 0, stream>>>(emb, B2, ee);
  k_norm_z  <<<dim3(N_TOK),       dim3(256), 0, stream>>>(z, A2);
  k_pass1   <<<dim3(NCH, 256),    dim3(256), 0, stream>>>(A2, B2, ee, sM, sZ, sE, cand, cbc);
  k_merge   <<<dim3(N_TOK / 256), dim3(256), 0, stream>>>(sM, sZ, sE, mL, C2, scal);
  k_scatter <<<dim3(NBLK),        dim3(256), 0, stream>>>(cand, cbc, C2, mL, colsum, ntList, ntc);
  k_refine  <<<dim3(1024),        dim3(256), 0, stream>>>(z, emb, ntList, ntc, rowkey);
  k_fidx    <<<dim3(N_TOK / 256), dim3(256), 0, stream>>>(rowkey, idxI, out + 4194308);
  k_zq      <<<dim3(N_TOK),       dim3(256), 0, stream>>>(A2, B2, idxI, qids, out, scal);
  k_avgent  <<<dim3(N_E / 256),   dim3(256), 0, stream>>>(colsum, scal);
  k_final   <<<dim3(1),           dim3(256), 0, stream>>>(idxI, qids, scal, out);
}